// Round 4
// baseline (145.235 us; speedup 1.0000x reference)
//
#include <hip/hip_runtime.h>

// ws layout: C[n*4 + w], n in [0,81) Pauli strings over {I,Y,Z}^4 (d0*27+d1*9+d2*3+d3),
// then 8 replicas of 8 partial sums at WS_SUMS.
#define WS_SUMS   352
#define N_REP     8

// ---------------------------------------------------------------------------
// k_pre: evolve basis states -> U, M_w = U^dag Z_w U, then Pauli coefficients
// c_{w,P} = tr(sigma_P M_w)/16 for P in {I,Y,Z}^4. Zero the sum slots.
// ---------------------------------------------------------------------------
__global__ void k_pre(const float* __restrict__ W, float* __restrict__ ws){
  __shared__ float Ur[16][16];     // Ur[k][col] = Re U[k,col]
  __shared__ float Uim[16][16];
  __shared__ float Mr[4][16][16];  // Mr[w][j][i] = Re M_w[j,i]
  __shared__ float Mi[4][16][16];
  const int t = threadIdx.x;

  if (t < N_REP*8) ws[WS_SUMS + t] = 0.f;

  if (t < 16){
    float re[16], im[16];
    #pragma unroll
    for (int i = 0; i < 16; i++){ re[i] = 0.f; im[i] = 0.f; }
    re[t] = 1.f;

    #pragma unroll
    for (int l = 0; l < 2; l++){
      #pragma unroll
      for (int w = 0; w < 4; w++){
        const int m = 8 >> w;
        const float* g = W + (l*4 + w)*3;
        {
          float th = 0.5f*g[0], c = cosf(th), s = sinf(th);
          #pragma unroll
          for (int i0 = 0; i0 < 16; i0++) if (!(i0 & m)){
            int i1 = i0 | m;
            float a0r=re[i0], a0i=im[i0], a1r=re[i1], a1i=im[i1];
            re[i0] = c*a0r + s*a1i;  im[i0] = c*a0i - s*a1r;
            re[i1] = c*a1r + s*a0i;  im[i1] = c*a1i - s*a0r;
          }
        }
        {
          float th = 0.5f*g[1], c = cosf(th), s = sinf(th);
          #pragma unroll
          for (int i0 = 0; i0 < 16; i0++) if (!(i0 & m)){
            int i1 = i0 | m;
            float a0r=re[i0], a0i=im[i0], a1r=re[i1], a1i=im[i1];
            re[i0] = c*a0r - s*a1r;  im[i0] = c*a0i - s*a1i;
            re[i1] = s*a0r + c*a1r;  im[i1] = s*a0i + c*a1i;
          }
        }
        {
          float th = 0.5f*g[2], c = cosf(th), s = sinf(th);
          #pragma unroll
          for (int i0 = 0; i0 < 16; i0++) if (!(i0 & m)){
            int i1 = i0 | m;
            float a0r=re[i0], a0i=im[i0], a1r=re[i1], a1i=im[i1];
            re[i0] = c*a0r + s*a0i;  im[i0] = c*a0i - s*a0r;
            re[i1] = c*a1r - s*a1i;  im[i1] = c*a1i + s*a1r;
          }
        }
      }
      #pragma unroll
      for (int w = 0; w < 4; w++){
        const int mc = 8 >> w, mt = 8 >> ((w+1)&3);
        float nr[16], ni[16];
        #pragma unroll
        for (int i = 0; i < 16; i++){
          int src = (i & mc) ? (i ^ mt) : i;
          nr[i] = re[src]; ni[i] = im[src];
        }
        #pragma unroll
        for (int i = 0; i < 16; i++){ re[i] = nr[i]; im[i] = ni[i]; }
      }
    }
    #pragma unroll
    for (int k = 0; k < 16; k++){ Ur[k][t] = re[k]; Uim[k][t] = im[k]; }
  }
  __syncthreads();

  // M_w[j,i] = sum_k conj(U[k,j]) z_w(k) U[k,i]
  {
    const int j = t >> 4, i = t & 15;
    #pragma unroll
    for (int w = 0; w < 4; w++){
      const int zm = 8 >> w;
      float mr = 0.f, mi = 0.f;
      #pragma unroll
      for (int k = 0; k < 16; k++){
        float z = (k & zm) ? -1.f : 1.f;
        float ar = Ur[k][j], ai = Uim[k][j];
        float br = Ur[k][i], bi = Uim[k][i];
        mr += z*(ar*br + ai*bi);
        mi += z*(ar*bi - ai*br);
      }
      Mr[w][j][i] = mr;  Mi[w][j][i] = mi;
    }
  }
  __syncthreads();

  // c_{w,P} = (1/16) sum_i sign_i * {+Re,+Im,-Re,-Im}[mY&3] of M_w[i^maskY, i]
  if (t < 81){
    int d0 = t/27, rem = t - d0*27;
    int d1 = rem/9;  rem -= d1*9;
    int d2 = rem/3,  d3 = rem - d2*3;
    int maskY = 0, maskZ = 0, mY = 0;
    if (d0 == 1){ maskY |= 8; mY++; } else if (d0 == 2) maskZ |= 8;
    if (d1 == 1){ maskY |= 4; mY++; } else if (d1 == 2) maskZ |= 4;
    if (d2 == 1){ maskY |= 2; mY++; } else if (d2 == 2) maskZ |= 2;
    if (d3 == 1){ maskY |= 1; mY++; } else if (d3 == 2) maskZ |= 1;
    const int mall = maskY | maskZ;
    const int sel  = mY & 3;
    #pragma unroll
    for (int w = 0; w < 4; w++){
      float c = 0.f;
      for (int i = 0; i < 16; i++){
        int j = i ^ maskY;
        float s = (__popc(i & mall) & 1) ? -1.f : 1.f;
        float val = (sel == 0) ?  Mr[w][j][i]
                  : (sel == 1) ?  Mi[w][j][i]
                  : (sel == 2) ? -Mr[w][j][i]
                  :              -Mi[w][j][i];
        c += s * val;
      }
      ws[t*4 + w] = c * 0.0625f;
    }
  }
}

// ---------------------------------------------------------------------------
// k_main: one thread = one batch row. Register pooling, full-angle sincos,
// Pauli-basis contraction (81 coeffs/wire, SGPR-broadcast), coalesced float4
// q-store, shuffle reduction + replicated atomics.
// ---------------------------------------------------------------------------
__global__ __launch_bounds__(256) void k_main(const float* __restrict__ x,
                                              const float* __restrict__ C,
                                              float* __restrict__ qout,
                                              float* __restrict__ sums){
  __shared__ float wred[4][8];
  const int t = threadIdx.x;
  const size_t row = (size_t)blockIdx.x*256 + t;
  const float4* rp = (const float4*)(x + row*144);

  // pooling: quadrant sums. float4 #p: img-row p/3 (top iff p<18),
  // col-group p%3 (0: all-left, 1: split, 2: all-right)
  float aTL = 0.f, aTR = 0.f, aBL = 0.f, aBR = 0.f;
  #pragma unroll
  for (int ph = 0; ph < 3; ph++){
    float4 buf[12];
    #pragma unroll
    for (int j = 0; j < 12; j++) buf[j] = rp[ph*12 + j];
    #pragma unroll
    for (int j = 0; j < 12; j++){
      const int p  = ph*12 + j;
      const int cg = p % 3;
      float s01 = buf[j].x + buf[j].y, s23 = buf[j].z + buf[j].w;
      float L = (cg == 0) ? (s01 + s23) : ((cg == 1) ? s01 : 0.f);
      float R = (cg == 2) ? (s01 + s23) : ((cg == 1) ? s23 : 0.f);
      if (p < 18){ aTL += L; aTR += R; } else { aBL += L; aBR += R; }
    }
  }

  // full angles (quadrant means) and per-wire Pauli factors g = (1, -sin, cos)
  const float inv = 1.f/36.f;
  float s0,c0,s1,c1,s2,c2,s3,c3;
  __sincosf(aTL*inv, &s0, &c0);
  __sincosf(aTR*inv, &s1, &c1);
  __sincosf(aBL*inv, &s2, &c2);
  __sincosf(aBR*inv, &s3, &c3);
  const float g0[3] = {1.f, -s0, c0};
  const float g1[3] = {1.f, -s1, c1};
  const float g2[3] = {1.f, -s2, c2};
  const float g3[3] = {1.f, -s3, c3};

  float G01[9], G23[9];
  #pragma unroll
  for (int a = 0; a < 3; a++)
    #pragma unroll
    for (int b = 0; b < 3; b++){
      G01[a*3+b] = g0[a]*g1[b];
      G23[a*3+b] = g2[a]*g3[b];
    }

  // q_w = sum_n C[n*4+w] * G01[n/9]*G23[n%9] -- C indices wave-uniform -> SGPR
  float q0=0.f, q1=0.f, q2=0.f, q3=0.f;
  #pragma unroll
  for (int m = 0; m < 9; m++){
    #pragma unroll
    for (int l = 0; l < 9; l++){
      const int n = m*9 + l;
      float g = G01[m]*G23[l];
      q0 = fmaf(C[n*4+0], g, q0);
      q1 = fmaf(C[n*4+1], g, q1);
      q2 = fmaf(C[n*4+2], g, q2);
      q3 = fmaf(C[n*4+3], g, q3);
    }
  }

  ((float4*)qout)[row] = make_float4(q0, q1, q2, q3);   // coalesced 16B/lane

  // block reduction of sum/sumsq for the 4 wires
  float red[8] = {q0, q1, q2, q3, q0*q0, q1*q1, q2*q2, q3*q3};
  #pragma unroll
  for (int off = 32; off >= 1; off >>= 1){
    #pragma unroll
    for (int k = 0; k < 8; k++) red[k] += __shfl_down(red[k], off, 64);
  }
  const int lane = t & 63, wv = t >> 6;
  if (lane == 0){
    #pragma unroll
    for (int k = 0; k < 8; k++) wred[wv][k] = red[k];
  }
  __syncthreads();
  if (t < 8){
    float s = wred[0][t] + wred[1][t] + wred[2][t] + wred[3][t];
    atomicAdd(&sums[(blockIdx.x & (N_REP-1))*8 + t], s);
  }
}

// ---------------------------------------------------------------------------
// k_statsnorm: recompute scale/shift from the replicated sums (uniform scalar
// loads), then normalize one float4 of out per thread, in place.
// ---------------------------------------------------------------------------
__global__ __launch_bounds__(256) void k_statsnorm(float* __restrict__ out,
                                                   const float* __restrict__ sums,
                                                   const float* __restrict__ gamma,
                                                   const float* __restrict__ beta,
                                                   float invB){
  const int idx = blockIdx.x*256 + threadIdx.x;
  float sc[4], sh[4];
  #pragma unroll
  for (int w = 0; w < 4; w++){
    float s1 = 0.f, s2 = 0.f;
    #pragma unroll
    for (int rep = 0; rep < N_REP; rep++){
      s1 += sums[rep*8 + w];
      s2 += sums[rep*8 + 4 + w];
    }
    float mean  = s1 * invB;
    float var   = s2 * invB - mean*mean;
    float scale = gamma[w] * rsqrtf(var + 1e-5f);
    sc[w] = scale;
    sh[w] = fmaf(-mean, scale, beta[w]);
  }
  float4* o4 = (float4*)out;
  float4 qv = o4[idx];
  qv.x = fmaf(qv.x, sc[0], sh[0]);
  qv.y = fmaf(qv.y, sc[1], sh[1]);
  qv.z = fmaf(qv.z, sc[2], sh[2]);
  qv.w = fmaf(qv.w, sc[3], sh[3]);
  o4[idx] = qv;
}

// ---------------------------------------------------------------------------
extern "C" void kernel_launch(void* const* d_in, const int* in_sizes, int n_in,
                              void* d_out, int out_size, void* d_ws, size_t ws_size,
                              hipStream_t stream){
  const float* x     = (const float*)d_in[0];
  const float* W     = (const float*)d_in[1];
  const float* gamma = (const float*)d_in[2];
  const float* beta  = (const float*)d_in[3];
  float* ws  = (float*)d_ws;
  float* out = (float*)d_out;
  const int B = in_sizes[0] / 144;

  k_pre<<<1, 256, 0, stream>>>(W, ws);
  k_main<<<B/256, 256, 0, stream>>>(x, ws, out, ws + WS_SUMS);
  k_statsnorm<<<B/256, 256, 0, stream>>>(out, ws + WS_SUMS, gamma, beta, 1.f/(float)B);
}

// Round 5
// 143.549 us; speedup vs baseline: 1.0117x; 1.0117x over previous
//
#include <hip/hip_runtime.h>

// ws layout: C[n*4 + w], n in [0,81) Pauli strings over {I,Y,Z}^4 (d0*27+d1*9+d2*3+d3),
// then 8 replicas of 8 partial sums at WS_SUMS.
#define WS_SUMS   352
#define N_REP     8

// ---------------------------------------------------------------------------
// k_pre: evolve basis states -> U, M_w = U^dag Z_w U, then Pauli coefficients
// c_{w,P} = tr(sigma_P M_w)/16 for P in {I,Y,Z}^4. Zero the sum slots.
// ---------------------------------------------------------------------------
__global__ void k_pre(const float* __restrict__ W, float* __restrict__ ws){
  __shared__ float Ur[16][16];     // Ur[k][col] = Re U[k,col]
  __shared__ float Uim[16][16];
  __shared__ float Mr[4][16][16];  // Mr[w][j][i] = Re M_w[j,i]
  __shared__ float Mi[4][16][16];
  const int t = threadIdx.x;

  if (t < N_REP*8) ws[WS_SUMS + t] = 0.f;

  if (t < 16){
    float re[16], im[16];
    #pragma unroll
    for (int i = 0; i < 16; i++){ re[i] = 0.f; im[i] = 0.f; }
    re[t] = 1.f;

    #pragma unroll
    for (int l = 0; l < 2; l++){
      #pragma unroll
      for (int w = 0; w < 4; w++){
        const int m = 8 >> w;
        const float* g = W + (l*4 + w)*3;
        {
          float th = 0.5f*g[0], c = cosf(th), s = sinf(th);
          #pragma unroll
          for (int i0 = 0; i0 < 16; i0++) if (!(i0 & m)){
            int i1 = i0 | m;
            float a0r=re[i0], a0i=im[i0], a1r=re[i1], a1i=im[i1];
            re[i0] = c*a0r + s*a1i;  im[i0] = c*a0i - s*a1r;
            re[i1] = c*a1r + s*a0i;  im[i1] = c*a1i - s*a0r;
          }
        }
        {
          float th = 0.5f*g[1], c = cosf(th), s = sinf(th);
          #pragma unroll
          for (int i0 = 0; i0 < 16; i0++) if (!(i0 & m)){
            int i1 = i0 | m;
            float a0r=re[i0], a0i=im[i0], a1r=re[i1], a1i=im[i1];
            re[i0] = c*a0r - s*a1r;  im[i0] = c*a0i - s*a1i;
            re[i1] = s*a0r + c*a1r;  im[i1] = s*a0i + c*a1i;
          }
        }
        {
          float th = 0.5f*g[2], c = cosf(th), s = sinf(th);
          #pragma unroll
          for (int i0 = 0; i0 < 16; i0++) if (!(i0 & m)){
            int i1 = i0 | m;
            float a0r=re[i0], a0i=im[i0], a1r=re[i1], a1i=im[i1];
            re[i0] = c*a0r + s*a0i;  im[i0] = c*a0i - s*a0r;
            re[i1] = c*a1r - s*a1i;  im[i1] = c*a1i + s*a1r;
          }
        }
      }
      #pragma unroll
      for (int w = 0; w < 4; w++){
        const int mc = 8 >> w, mt = 8 >> ((w+1)&3);
        float nr[16], ni[16];
        #pragma unroll
        for (int i = 0; i < 16; i++){
          int src = (i & mc) ? (i ^ mt) : i;
          nr[i] = re[src]; ni[i] = im[src];
        }
        #pragma unroll
        for (int i = 0; i < 16; i++){ re[i] = nr[i]; im[i] = ni[i]; }
      }
    }
    #pragma unroll
    for (int k = 0; k < 16; k++){ Ur[k][t] = re[k]; Uim[k][t] = im[k]; }
  }
  __syncthreads();

  // M_w[j,i] = sum_k conj(U[k,j]) z_w(k) U[k,i]
  {
    const int j = t >> 4, i = t & 15;
    #pragma unroll
    for (int w = 0; w < 4; w++){
      const int zm = 8 >> w;
      float mr = 0.f, mi = 0.f;
      #pragma unroll
      for (int k = 0; k < 16; k++){
        float z = (k & zm) ? -1.f : 1.f;
        float ar = Ur[k][j], ai = Uim[k][j];
        float br = Ur[k][i], bi = Uim[k][i];
        mr += z*(ar*br + ai*bi);
        mi += z*(ar*bi - ai*br);
      }
      Mr[w][j][i] = mr;  Mi[w][j][i] = mi;
    }
  }
  __syncthreads();

  // c_{w,P} = (1/16) sum_i sign_i * {+Re,+Im,-Re,-Im}[mY&3] of M_w[i^maskY, i]
  if (t < 81){
    int d0 = t/27, rem = t - d0*27;
    int d1 = rem/9;  rem -= d1*9;
    int d2 = rem/3,  d3 = rem - d2*3;
    int maskY = 0, maskZ = 0, mY = 0;
    if (d0 == 1){ maskY |= 8; mY++; } else if (d0 == 2) maskZ |= 8;
    if (d1 == 1){ maskY |= 4; mY++; } else if (d1 == 2) maskZ |= 4;
    if (d2 == 1){ maskY |= 2; mY++; } else if (d2 == 2) maskZ |= 2;
    if (d3 == 1){ maskY |= 1; mY++; } else if (d3 == 2) maskZ |= 1;
    const int mall = maskY | maskZ;
    const int sel  = mY & 3;
    #pragma unroll
    for (int w = 0; w < 4; w++){
      float c = 0.f;
      #pragma unroll
      for (int i = 0; i < 16; i++){
        int j = i ^ maskY;
        float s = (__popc(i & mall) & 1) ? -1.f : 1.f;
        float val = (sel == 0) ?  Mr[w][j][i]
                  : (sel == 1) ?  Mi[w][j][i]
                  : (sel == 2) ? -Mr[w][j][i]
                  :              -Mi[w][j][i];
        c += s * val;
      }
      ws[t*4 + w] = c * 0.0625f;
    }
  }
}

// ---------------------------------------------------------------------------
// k_main: 4 lanes per batch row (64 rows/block, 2048 blocks). Coalesced
// 64B-per-group loads (16 lines/instr), register pooling, shfl_xor butterfly,
// lane k contracts wire k (81 FMA, L1-broadcast C), coalesced q-store,
// shuffle reduction + replicated atomics.
// ---------------------------------------------------------------------------
__global__ __launch_bounds__(256) void k_main(const float* __restrict__ x,
                                              const float* __restrict__ C,
                                              float* __restrict__ qout,
                                              float* __restrict__ sums){
  __shared__ float wred[4][8];
  const int t = threadIdx.x;
  const int k = t & 3;                                  // lane-in-row
  const size_t row = (size_t)blockIdx.x*64 + (t >> 2);
  const float4* rp4 = (const float4*)(x) + row*36;

  // 9 loads, 9-deep MLP; lane 4b+k reads float4 #(j*4+k) of row b
  float4 v[9];
  #pragma unroll
  for (int j = 0; j < 9; j++) v[j] = rp4[j*4 + k];

  // pooling partials: p = j*4+k; top iff p<18; col-group cg = p%3
  // (0: all-left, 1: split, 2: all-right)
  float aTL = 0.f, aTR = 0.f, aBL = 0.f, aBR = 0.f;
  #pragma unroll
  for (int j = 0; j < 9; j++){
    const int p  = j*4 + k;
    const int cg = p % 3;
    float s01 = v[j].x + v[j].y, s23 = v[j].z + v[j].w;
    float L = (cg == 0) ? (s01 + s23) : ((cg == 1) ? s01 : 0.f);
    float R = (cg == 2) ? (s01 + s23) : ((cg == 1) ? s23 : 0.f);
    if (p < 18){ aTL += L; aTR += R; } else { aBL += L; aBR += R; }
  }

  // butterfly over the aligned 4-lane group -> all lanes hold full quadrant sums
  #pragma unroll
  for (int m = 1; m <= 2; m <<= 1){
    aTL += __shfl_xor(aTL, m, 64);
    aTR += __shfl_xor(aTR, m, 64);
    aBL += __shfl_xor(aBL, m, 64);
    aBR += __shfl_xor(aBR, m, 64);
  }

  // full angles (quadrant means), per-wire Pauli factors g = (1, -sin, cos)
  const float inv = 1.f/36.f;
  float s0,c0,s1,c1,s2,c2,s3,c3;
  __sincosf(aTL*inv, &s0, &c0);
  __sincosf(aTR*inv, &s1, &c1);
  __sincosf(aBL*inv, &s2, &c2);
  __sincosf(aBR*inv, &s3, &c3);
  const float g0[3] = {1.f, -s0, c0};
  const float g1[3] = {1.f, -s1, c1};
  const float g2[3] = {1.f, -s2, c2};
  const float g3[3] = {1.f, -s3, c3};

  float G01[9], G23[9];
  #pragma unroll
  for (int a = 0; a < 3; a++)
    #pragma unroll
    for (int b = 0; b < 3; b++){
      G01[a*3+b] = g0[a]*g1[b];
      G23[a*3+b] = g2[a]*g3[b];
    }

  // lane k: q_k = sum_n C[n*4+k] * G01[n/9]*G23[n%9]
  // group's 4 lanes read 16B-contiguous -> single L1 line, broadcast across groups
  float q = 0.f;
  #pragma unroll
  for (int m = 0; m < 9; m++){
    #pragma unroll
    for (int l = 0; l < 9; l++){
      const int n = m*9 + l;
      q = fmaf(C[n*4 + k], G01[m]*G23[l], q);
    }
  }

  qout[(size_t)blockIdx.x*256 + t] = q;       // coalesced 4B/lane

  // per-wire reduction: lanes with equal (lane&3) hold the same wire
  float qs = q, q2 = q*q;
  #pragma unroll
  for (int off = 32; off >= 4; off >>= 1){
    qs += __shfl_down(qs, off, 64);
    q2 += __shfl_down(q2, off, 64);
  }
  const int lane = t & 63, wv = t >> 6;
  if (lane < 4){ wred[wv][lane] = qs; wred[wv][lane+4] = q2; }
  __syncthreads();
  if (t < 8){
    float s = wred[0][t] + wred[1][t] + wred[2][t] + wred[3][t];
    atomicAdd(&sums[(blockIdx.x & (N_REP-1))*8 + t], s);
  }
}

// ---------------------------------------------------------------------------
// k_statsnorm: recompute scale/shift from the replicated sums (uniform scalar
// loads), then normalize one float4 of out per thread, in place.
// ---------------------------------------------------------------------------
__global__ __launch_bounds__(256) void k_statsnorm(float* __restrict__ out,
                                                   const float* __restrict__ sums,
                                                   const float* __restrict__ gamma,
                                                   const float* __restrict__ beta,
                                                   float invB){
  const int idx = blockIdx.x*256 + threadIdx.x;
  float sc[4], sh[4];
  #pragma unroll
  for (int w = 0; w < 4; w++){
    float s1 = 0.f, s2 = 0.f;
    #pragma unroll
    for (int rep = 0; rep < N_REP; rep++){
      s1 += sums[rep*8 + w];
      s2 += sums[rep*8 + 4 + w];
    }
    float mean  = s1 * invB;
    float var   = s2 * invB - mean*mean;
    float scale = gamma[w] * rsqrtf(var + 1e-5f);
    sc[w] = scale;
    sh[w] = fmaf(-mean, scale, beta[w]);
  }
  float4* o4 = (float4*)out;
  float4 qv = o4[idx];
  qv.x = fmaf(qv.x, sc[0], sh[0]);
  qv.y = fmaf(qv.y, sc[1], sh[1]);
  qv.z = fmaf(qv.z, sc[2], sh[2]);
  qv.w = fmaf(qv.w, sc[3], sh[3]);
  o4[idx] = qv;
}

// ---------------------------------------------------------------------------
extern "C" void kernel_launch(void* const* d_in, const int* in_sizes, int n_in,
                              void* d_out, int out_size, void* d_ws, size_t ws_size,
                              hipStream_t stream){
  const float* x     = (const float*)d_in[0];
  const float* W     = (const float*)d_in[1];
  const float* gamma = (const float*)d_in[2];
  const float* beta  = (const float*)d_in[3];
  float* ws  = (float*)d_ws;
  float* out = (float*)d_out;
  const int B = in_sizes[0] / 144;

  k_pre<<<1, 256, 0, stream>>>(W, ws);
  k_main<<<B/64, 256, 0, stream>>>(x, ws, out, ws + WS_SUMS);
  k_statsnorm<<<B/256, 256, 0, stream>>>(out, ws + WS_SUMS, gamma, beta, 1.f/(float)B);
}